// Round 8
// baseline (419.909 us; speedup 1.0000x reference)
//
#include <hip/hip_runtime.h>

typedef __attribute__((ext_vector_type(8))) short bfrag;
typedef __attribute__((ext_vector_type(4))) float ffrag;

namespace {
constexpr int Sc = 1024, Dc = 64;
constexpr int P2 = 72;          // bf16 LDS pitch (144 B) for MFMA-read tiles
constexpr int PQ = 64;          // Qs pitch — hoist read is one-time, no pad needed
constexpr int PW = 33;          // f32 pitch for Ts/Ws — bank-spread for row reads
constexpr float SCALE = 0.125f; // 1/sqrt(64)
}

__device__ __forceinline__ unsigned short f2bf(float f) {
    unsigned u = __builtin_bit_cast(unsigned, f);
    u += 0x7fffu + ((u >> 16) & 1u);
    return (unsigned short)(u >> 16);
}
__device__ __forceinline__ bfrag pack8(float4 a, float4 b) {
    bfrag r;
    r[0] = (short)f2bf(a.x); r[1] = (short)f2bf(a.y);
    r[2] = (short)f2bf(a.z); r[3] = (short)f2bf(a.w);
    r[4] = (short)f2bf(b.x); r[5] = (short)f2bf(b.y);
    r[6] = (short)f2bf(b.z); r[7] = (short)f2bf(b.w);
    return r;
}
#define MFMA(a, b, c) __builtin_amdgcn_mfma_f32_16x16x32_bf16((a), (b), (c), 0, 0, 0)

#define BAR()                                             \
    do {                                                  \
        asm volatile("s_waitcnt lgkmcnt(0)" ::: "memory");\
        __builtin_amdgcn_s_barrier();                     \
    } while (0)

// ============== K1: parallel row-sum (l) + masked-region zero-fill ==============
// One block per (qtile,ktile,bh). kt>qt: stream zeros into the masked p tile.
// kt<=qt: compute this tile's exp-sums per row and atomicAdd into lws[bh][row].
// No inner serialization — converts pass 1 (17 serial windows/block) into a
// fully parallel kernel.
__global__ __launch_bounds__(256, 4)
void lsum_zero(const float* __restrict__ Qg, const float* __restrict__ Kg,
               const float* __restrict__ pek, float* __restrict__ pbuf,
               float* __restrict__ lws)
{
    const int qt = (int)blockIdx.x >> 4;
    const int kt = (int)blockIdx.x & 15;
    const int bh = blockIdx.y;
    const int tid = threadIdx.x;
    float* pbh = pbuf + (size_t)bh * Sc * Sc;

    if (kt > qt) {   // fully-masked tile: zero p, done
        const int rr = tid >> 4, c4 = tid & 15;
        const float4 z = make_float4(0.f, 0.f, 0.f, 0.f);
        float* base = pbh + (size_t)(qt * 64 + rr) * Sc + kt * 64 + c4 * 4;
        #pragma unroll
        for (int s = 0; s < 4; ++s)
            *(float4*)(base + (size_t)(s * 16) * Sc) = z;
        return;
    }

    // LDS: Qs [64][64] 8192 | Ks [64][72] 9216 | Ps [48][72] 6912 | Ts [64][33] 8448 = 32768
    __shared__ __align__(16) char sm[32768];
    unsigned short* Qs = (unsigned short*)sm;
    unsigned short* Ks = (unsigned short*)(sm + 8192);
    unsigned short* Ps = (unsigned short*)(sm + 17408);
    float* Ts = (float*)(sm + 24320);

    const int wv = tid >> 6, lane = tid & 63, n = lane & 15, quad = lane >> 4;
    const int qrow = wv * 16 + quad * 4;
    const int sr = tid >> 2, sc4 = (tid & 3) * 16;
    const float* Qbh = Qg + (size_t)bh * Sc * Dc;
    const float* Kbh = Kg + (size_t)bh * Sc * Dc;

    {   // stage Q tile
        const float* src = Qbh + (size_t)(qt * 64 + sr) * Dc + sc4;
        float4 a = *(const float4*)(src);
        float4 b = *(const float4*)(src + 4);
        float4 c = *(const float4*)(src + 8);
        float4 d = *(const float4*)(src + 12);
        *(bfrag*)&Qs[sr * PQ + sc4]     = pack8(a, b);
        *(bfrag*)&Qs[sr * PQ + sc4 + 8] = pack8(c, d);
    }
    {   // stage K tile
        const float* src = Kbh + (size_t)(kt * 64 + sr) * Dc + sc4;
        float4 a = *(const float4*)(src);
        float4 b = *(const float4*)(src + 4);
        float4 c = *(const float4*)(src + 8);
        float4 d = *(const float4*)(src + 12);
        *(bfrag*)&Ks[sr * P2 + sc4]     = pack8(a, b);
        *(bfrag*)&Ks[sr * P2 + sc4 + 8] = pack8(c, d);
    }
    if (tid < 135) {   // zero pe_k rows 33..47
        bfrag z = {};
        *(bfrag*)&Ps[33 * P2 + tid * 8] = z;
    }
    if (tid < 132) {   // stage pe_k rows 0..32
        int r = tid >> 2, c0 = (tid & 3) * 16;
        const float* src = pek + (size_t)r * Dc + c0;
        float4 a = *(const float4*)(src);
        float4 b = *(const float4*)(src + 4);
        float4 c = *(const float4*)(src + 8);
        float4 d = *(const float4*)(src + 12);
        *(bfrag*)&Ps[r * P2 + c0]     = pack8(a, b);
        *(bfrag*)&Ps[r * P2 + c0 + 8] = pack8(c, d);
    }
    __syncthreads();

    bfrag qa0 = *(bfrag*)&Qs[(wv * 16 + n) * PQ + quad * 8];
    bfrag qa1 = *(bfrag*)&Qs[(wv * 16 + n) * PQ + 32 + quad * 8];

    // Ts = Q . pe_k^T
    #pragma unroll
    for (int sub = 0; sub < 3; ++sub) {
        bfrag b0 = *(bfrag*)&Ps[(sub * 16 + n) * P2 + quad * 8];
        bfrag b1 = *(bfrag*)&Ps[(sub * 16 + n) * P2 + 32 + quad * 8];
        ffrag c = {};
        c = MFMA(qa0, b0, c);
        c = MFMA(qa1, b1, c);
        int j = sub * 16 + n;
        if (j <= 32) {
            #pragma unroll
            for (int reg = 0; reg < 4; ++reg)
                Ts[(qrow + reg) * PW + j] = c[reg];
        }
    }
    __syncthreads();

    float ts0[4];
    #pragma unroll
    for (int reg = 0; reg < 4; ++reg) ts0[reg] = Ts[(qrow + reg) * PW];

    const bool bnd = (kt >= qt - 1);
    float ls[4] = {0.f, 0.f, 0.f, 0.f};
    #pragma unroll
    for (int sub = 0; sub < 4; ++sub) {
        bfrag b0 = *(bfrag*)&Ks[(sub * 16 + n) * P2 + quad * 8];
        bfrag b1 = *(bfrag*)&Ks[(sub * 16 + n) * P2 + 32 + quad * 8];
        ffrag c = {};
        c = MFMA(qa0, b0, c);
        c = MFMA(qa1, b1, c);
        const int k = kt * 64 + sub * 16 + n;
        if (!bnd) {
            #pragma unroll
            for (int reg = 0; reg < 4; ++reg)
                ls[reg] += __expf((c[reg] + ts0[reg]) * SCALE);
        } else {
            #pragma unroll
            for (int reg = 0; reg < 4; ++reg) {
                int jrel = k - (qt * 64 + qrow + reg) + 32;
                if (jrel <= 32) {
                    int jcl = jrel < 0 ? 0 : jrel;
                    ls[reg] += __expf((c[reg] + Ts[(qrow + reg) * PW + jcl]) * SCALE);
                }
            }
        }
    }
    #pragma unroll
    for (int reg = 0; reg < 4; ++reg) {
        float l = ls[reg];
        l += __shfl_xor(l, 1);
        l += __shfl_xor(l, 2);
        l += __shfl_xor(l, 4);
        l += __shfl_xor(l, 8);
        if (n == 0)
            atomicAdd(&lws[(size_t)bh * Sc + qt * 64 + qrow + reg], l);
    }
}

// ============== K2: pass-2-only main kernel (rinv from lws) ==============
// Paired q-tiles (512 blocks, balanced); pipelined QK(kt) || PV(kt-1)+dump,
// 1 barrier/kt. Pass 1 and the zero-fill have moved to lsum_zero.
__global__ __launch_bounds__(256, 2)
void relattn(const float* __restrict__ Qg, const float* __restrict__ Kg,
             const float* __restrict__ Vg, const float* __restrict__ pek,
             const float* __restrict__ pev, float* __restrict__ outg,
             float* __restrict__ pbuf, const float* __restrict__ lws)
{
    // LDS arena (72448 B, 2 blocks/CU): Ks0|Ks1|Vt0|Vt1|Pt0|Pt1 9216 each |
    // Ts 8448 | QsArena 8704 (Qs aliased by Ws+W0). Ot aliases Ks0+Ks1.
    __shared__ __align__(16) char smem[72448];
    unsigned short* Ks0 = (unsigned short*)smem;
    unsigned short* Ks1 = (unsigned short*)(smem + 9216);
    unsigned short* Vt0 = (unsigned short*)(smem + 18432);
    unsigned short* Vt1 = (unsigned short*)(smem + 27648);
    unsigned short* Pt0 = (unsigned short*)(smem + 36864);
    unsigned short* Pt1 = (unsigned short*)(smem + 46080);
    float* Ts = (float*)(smem + 55296);                    // [64][33]
    unsigned short* Qs = (unsigned short*)(smem + 63744);  // [64][64]
    float* Ws = (float*)(smem + 63744);                    // [64][33], aliases Qs
    float* W0 = (float*)(smem + 72192);                    // [64]
    float* Ot = (float*)smem;                              // [64][68], aliases Ks0+Ks1

    const int tid  = threadIdx.x;
    const int bh   = blockIdx.y;
    const int wv   = tid >> 6;
    const int lane = tid & 63;
    const int n    = lane & 15;
    const int quad = lane >> 4;

    const float* Qbh = Qg + (size_t)bh * Sc * Dc;
    const float* Kbh = Kg + (size_t)bh * Sc * Dc;
    const float* Vbh = Vg + (size_t)bh * Sc * Dc;
    float* pbh = pbuf + (size_t)bh * Sc * Sc;
    float* obh = outg + (size_t)bh * Sc * Dc;

    const int sr  = tid >> 2;           // staging row 0..63
    const int sc4 = (tid & 3) * 16;     // staging col (floats)
    const int kp  = tid & 31;           // V-transpose k-pair
    const int vd0 = (tid >> 5) * 8;     // V-transpose d base

    const int rr = tid >> 4;            // dump row 0..15
    const int c4 = tid & 15;            // dump float4 col

    for (int half = 0; half < 2; ++half) {
        const int qt = half ? (15 - (int)blockIdx.x) : (int)blockIdx.x;
        const int qrow = wv * 16 + quad * 4;

        BAR();   // previous half's epilogue LDS reads done

        // ---- rinv from lws (written by lsum_zero; stream-ordered) ----
        float rinv[4];
        #pragma unroll
        for (int reg = 0; reg < 4; ++reg)
            rinv[reg] = 1.f / lws[(size_t)bh * Sc + qt * 64 + qrow + reg];

        // ---- issue K[0] loads ----
        float4 k0a, k0b, k0c, k0d;
        {
            const float* ksrc = Kbh + (size_t)sr * Dc + sc4;
            k0a = *(const float4*)(ksrc);
            k0b = *(const float4*)(ksrc + 4);
            k0c = *(const float4*)(ksrc + 8);
            k0d = *(const float4*)(ksrc + 12);
        }
        // ---- stage Q tile ----
        {
            const float* src = Qbh + (size_t)(qt * 64 + sr) * Dc + sc4;
            float4 a = *(const float4*)(src);
            float4 b = *(const float4*)(src + 4);
            float4 c = *(const float4*)(src + 8);
            float4 d = *(const float4*)(src + 12);
            *(bfrag*)&Qs[sr * PQ + sc4]     = pack8(a, b);
            *(bfrag*)&Qs[sr * PQ + sc4 + 8] = pack8(c, d);
        }
        // ---- stage pe_k into Ks1 (rows 0..32; zero 33..47) ----
        for (int i = tid; i < 135; i += 256) {
            bfrag z = {};
            *(bfrag*)&Ks1[33 * P2 + i * 8] = z;
        }
        if (tid < 132) {
            int r = tid >> 2, c0 = (tid & 3) * 16;
            const float* src = pek + (size_t)r * Dc + c0;
            float4 a = *(const float4*)(src);
            float4 b = *(const float4*)(src + 4);
            float4 c = *(const float4*)(src + 8);
            float4 d = *(const float4*)(src + 12);
            *(bfrag*)&Ks1[r * P2 + c0]     = pack8(a, b);
            *(bfrag*)&Ks1[r * P2 + c0 + 8] = pack8(c, d);
        }
        BAR();

        // ---- hoist Q A-frags; Qs dead afterwards ----
        bfrag qa0 = *(bfrag*)&Qs[(wv * 16 + n) * PQ + quad * 8];
        bfrag qa1 = *(bfrag*)&Qs[(wv * 16 + n) * PQ + 32 + quad * 8];

        // ---- Ts = Q . pe_k^T (from Ks1) ----
        #pragma unroll
        for (int sub = 0; sub < 3; ++sub) {
            bfrag b0 = *(bfrag*)&Ks1[(sub * 16 + n) * P2 + quad * 8];
            bfrag b1 = *(bfrag*)&Ks1[(sub * 16 + n) * P2 + 32 + quad * 8];
            ffrag c = {};
            c = MFMA(qa0, b0, c);
            c = MFMA(qa1, b1, c);
            int j = sub * 16 + n;
            if (j <= 32) {
                #pragma unroll
                for (int reg = 0; reg < 4; ++reg)
                    Ts[(qrow + reg) * PW + j] = c[reg];
            }
        }
        // ---- stage K[0]->Ks0; issue K[1], V[0] prefetches ----
        *(bfrag*)&Ks0[sr * P2 + sc4]     = pack8(k0a, k0b);
        *(bfrag*)&Ks0[sr * P2 + sc4 + 8] = pack8(k0c, k0d);
        float4 pka, pkb, pkc, pkd;
        if (qt >= 1) {
            const float* ksrc = Kbh + (size_t)(64 + sr) * Dc + sc4;
            pka = *(const float4*)(ksrc);
            pkb = *(const float4*)(ksrc + 4);
            pkc = *(const float4*)(ksrc + 8);
            pkd = *(const float4*)(ksrc + 12);
        }
        float4 pva, pvb, pvc, pvd;
        {
            const float* vsrc = Vbh + (size_t)(2 * kp) * Dc + vd0;
            pva = *(const float4*)(vsrc);
            pvb = *(const float4*)(vsrc + 4);
            pvc = *(const float4*)(vsrc + Dc);
            pvd = *(const float4*)(vsrc + Dc + 4);
        }
        BAR();   // Ts + K[0] visible; Qs free; Ks1 free for K[1]

        float ts0[4];
        #pragma unroll
        for (int reg = 0; reg < 4; ++reg) ts0[reg] = Ts[(qrow + reg) * PW];

        // ---- zero Ws (aliases Qs) ----
        for (int idx = tid; idx < 64 * PW; idx += 256) Ws[idx] = 0.f;
        BAR();   // Ws zero visible before first boundary window (qt<=1 case)

        // ====== pipelined main loop: QK(kt) || PV(kt-1)+dump, 1 barrier/kt ======
        ffrag oacc[4];
        #pragma unroll
        for (int i = 0; i < 4; ++i) { ffrag z = {}; oacc[i] = z; }

        for (int kt = 0; kt <= qt; ++kt) {
            const bool bnd = (kt >= qt - 1);
            unsigned short* Kc  = (kt & 1) ? Ks1 : Ks0;
            unsigned short* Kn  = (kt & 1) ? Ks0 : Ks1;
            unsigned short* Vc  = (kt & 1) ? Vt1 : Vt0;
            unsigned short* Vp  = (kt & 1) ? Vt0 : Vt1;
            unsigned short* Ptc = (kt & 1) ? Pt1 : Pt0;
            unsigned short* Ptp = (kt & 1) ? Pt0 : Pt1;

            // ---- QK(kt): scores -> Ptc (bf16, normalized), rel-v capture ----
            #pragma unroll
            for (int sub = 0; sub < 4; ++sub) {
                bfrag b0 = *(bfrag*)&Kc[(sub * 16 + n) * P2 + quad * 8];
                bfrag b1 = *(bfrag*)&Kc[(sub * 16 + n) * P2 + 32 + quad * 8];
                ffrag c = {};
                c = MFMA(qa0, b0, c);
                c = MFMA(qa1, b1, c);
                const int k = kt * 64 + sub * 16 + n;
                if (!bnd) {
                    #pragma unroll
                    for (int reg = 0; reg < 4; ++reg) {
                        float p = __expf((c[reg] + ts0[reg]) * SCALE) * rinv[reg];
                        Ptc[(qrow + reg) * P2 + sub * 16 + n] = (unsigned short)f2bf(p);
                    }
                } else {
                    #pragma unroll
                    for (int reg = 0; reg < 4; ++reg) {
                        int jrel = k - (qt * 64 + qrow + reg) + 32;
                        float p = 0.f;
                        if (jrel <= 32) {
                            int jcl = jrel < 0 ? 0 : jrel;
                            p = __expf((c[reg] + Ts[(qrow + reg) * PW + jcl]) * SCALE) * rinv[reg];
                        }
                        Ptc[(qrow + reg) * P2 + sub * 16 + n] = (unsigned short)f2bf(p);
                        if ((unsigned)(jrel - 1) < 32u) Ws[(qrow + reg) * PW + jrel - 1] = p;
                    }
                }
            }
            // ---- stage K[kt+1] -> Kn; V[kt] -> Vc ----
            if (kt < qt) {
                *(bfrag*)&Kn[sr * P2 + sc4]     = pack8(pka, pkb);
                *(bfrag*)&Kn[sr * P2 + sc4 + 8] = pack8(pkc, pkd);
            }
            {
                float r0[8] = {pva.x, pva.y, pva.z, pva.w, pvb.x, pvb.y, pvb.z, pvb.w};
                float r1[8] = {pvc.x, pvc.y, pvc.z, pvc.w, pvd.x, pvd.y, pvd.z, pvd.w};
                #pragma unroll
                for (int i = 0; i < 8; ++i) {
                    unsigned pk = (unsigned)f2bf(r0[i]) | ((unsigned)f2bf(r1[i]) << 16);
                    *(unsigned*)&Vc[(vd0 + i) * P2 + 2 * kp] = pk;
                }
            }
            // ---- issue next prefetches ----
            if (kt + 2 <= qt) {
                const float* ksrc = Kbh + (size_t)((kt + 2) * 64 + sr) * Dc + sc4;
                pka = *(const float4*)(ksrc);
                pkb = *(const float4*)(ksrc + 4);
                pkc = *(const float4*)(ksrc + 8);
                pkd = *(const float4*)(ksrc + 12);
            }
            if (kt + 1 <= qt) {
                const float* vsrc = Vbh + (size_t)((kt + 1) * 64 + 2 * kp) * Dc + vd0;
                pva = *(const float4*)(vsrc);
                pvb = *(const float4*)(vsrc + 4);
                pvc = *(const float4*)(vsrc + Dc);
                pvd = *(const float4*)(vsrc + Dc + 4);
            }
            // ---- PV(kt-1) + dump(kt-1) ----
            if (kt >= 1) {
                bfrag pb0 = *(bfrag*)&Ptp[(wv * 16 + n) * P2 + quad * 8];
                bfrag pb1 = *(bfrag*)&Ptp[(wv * 16 + n) * P2 + 32 + quad * 8];
                #pragma unroll
                for (int ds = 0; ds < 4; ++ds) {
                    bfrag va0 = *(bfrag*)&Vp[(ds * 16 + n) * P2 + quad * 8];
                    bfrag va1 = *(bfrag*)&Vp[(ds * 16 + n) * P2 + 32 + quad * 8];
                    oacc[ds] = MFMA(va0, pb0, oacc[ds]);
                    oacc[ds] = MFMA(va1, pb1, oacc[ds]);
                }
                float* base = pbh + ((size_t)(qt * 64 + rr) * Sc + (kt - 1) * 64 + c4 * 4);
                #pragma unroll
                for (int step = 0; step < 4; ++step) {
                    const int r = step * 16 + rr;
                    const unsigned short* ps = &Ptp[r * P2 + c4 * 4];
                    unsigned two0 = *(const unsigned*)(ps);
                    unsigned two1 = *(const unsigned*)(ps + 2);
                    float4 v;
                    v.x = __builtin_bit_cast(float, (two0 & 0xffffu) << 16);
                    v.y = __builtin_bit_cast(float, two0 & 0xffff0000u);
                    v.z = __builtin_bit_cast(float, (two1 & 0xffffu) << 16);
                    v.w = __builtin_bit_cast(float, two1 & 0xffff0000u);
                    *(float4*)(base + (size_t)(step * 16) * Sc) = v;
                }
            }
            BAR();   // window boundary
        }
        // ---- drain: PV(qt) + dump(qt) ----
        {
            unsigned short* Ptp = (qt & 1) ? Pt1 : Pt0;
            unsigned short* Vp  = (qt & 1) ? Vt1 : Vt0;
            bfrag pb0 = *(bfrag*)&Ptp[(wv * 16 + n) * P2 + quad * 8];
            bfrag pb1 = *(bfrag*)&Ptp[(wv * 16 + n) * P2 + 32 + quad * 8];
            #pragma unroll
            for (int ds = 0; ds < 4; ++ds) {
                bfrag va0 = *(bfrag*)&Vp[(ds * 16 + n) * P2 + quad * 8];
                bfrag va1 = *(bfrag*)&Vp[(ds * 16 + n) * P2 + 32 + quad * 8];
                oacc[ds] = MFMA(va0, pb0, oacc[ds]);
                oacc[ds] = MFMA(va1, pb1, oacc[ds]);
            }
            float* base = pbh + ((size_t)(qt * 64 + rr) * Sc + qt * 64 + c4 * 4);
            #pragma unroll
            for (int step = 0; step < 4; ++step) {
                const int r = step * 16 + rr;
                const unsigned short* ps = &Ptp[r * P2 + c4 * 4];
                unsigned two0 = *(const unsigned*)(ps);
                unsigned two1 = *(const unsigned*)(ps + 2);
                float4 v;
                v.x = __builtin_bit_cast(float, (two0 & 0xffffu) << 16);
                v.y = __builtin_bit_cast(float, two0 & 0xffff0000u);
                v.z = __builtin_bit_cast(float, (two1 & 0xffffu) << 16);
                v.w = __builtin_bit_cast(float, two1 & 0xffff0000u);
                *(float4*)(base + (size_t)(step * 16) * Sc) = v;
            }
        }
        BAR();   // all PV/dump LDS reads done before epilogue prep writes

        // ================= epilogue: rel-v term + store O =================
        if (tid < 64) {
            float s = 0.f;
            #pragma unroll
            for (int j = 0; j < 32; ++j) s += Ws[tid * PW + j];
            W0[tid] = 1.f - s;
        }
        {   // Pt0[q][jj] <- Ws (bf16)
            int q = tid >> 2, j0 = (tid & 3) * 8;
            #pragma unroll
            for (int i = 0; i < 8; i += 2) {
                unsigned pk = (unsigned)f2bf(Ws[q * PW + j0 + i]) |
                              ((unsigned)f2bf(Ws[q * PW + j0 + i + 1]) << 16);
                *(unsigned*)&Pt0[q * P2 + j0 + i] = pk;
            }
        }
        {   // Vt0[d][jj] <- pe_v[jj+1][d]
            int jj = tid >> 3, d0 = (tid & 7) * 8;
            const float* src = pev + (size_t)(jj + 1) * Dc + d0;
            float4 a = *(const float4*)(src);
            float4 b = *(const float4*)(src + 4);
            float vr[8] = {a.x, a.y, a.z, a.w, b.x, b.y, b.z, b.w};
            #pragma unroll
            for (int i = 0; i < 8; ++i)
                Vt0[(d0 + i) * P2 + jj] = (unsigned short)f2bf(vr[i]);
        }
        BAR();   // Pt0/Vt0/W0 prep visible
        {
            bfrag pb = *(bfrag*)&Pt0[(wv * 16 + n) * P2 + quad * 8];
            #pragma unroll
            for (int ds = 0; ds < 4; ++ds) {
                bfrag va = *(bfrag*)&Vt0[(ds * 16 + n) * P2 + quad * 8];
                oacc[ds] = MFMA(va, pb, oacc[ds]);
            }
        }
        float w0q = W0[wv * 16 + n];
        #pragma unroll
        for (int ds = 0; ds < 4; ++ds) {
            float4 ov;
            ov.x = oacc[ds][0] + w0q * pev[ds * 16 + quad * 4 + 0];
            ov.y = oacc[ds][1] + w0q * pev[ds * 16 + quad * 4 + 1];
            ov.z = oacc[ds][2] + w0q * pev[ds * 16 + quad * 4 + 2];
            ov.w = oacc[ds][3] + w0q * pev[ds * 16 + quad * 4 + 3];
            *(float4*)&Ot[(wv * 16 + n) * 68 + ds * 16 + quad * 4] = ov;
        }
        BAR();
        {
            int r = tid >> 2, c0 = (tid & 3) * 16;
            float* dst = obh + (size_t)(qt * 64 + r) * Dc + c0;
            *(float4*)(dst)      = *(float4*)&Ot[r * 68 + c0];
            *(float4*)(dst + 4)  = *(float4*)&Ot[r * 68 + c0 + 4];
            *(float4*)(dst + 8)  = *(float4*)&Ot[r * 68 + c0 + 8];
            *(float4*)(dst + 12) = *(float4*)&Ot[r * 68 + c0 + 12];
        }
    }
}

extern "C" void kernel_launch(void* const* d_in, const int* in_sizes, int n_in,
                              void* d_out, int out_size, void* d_ws, size_t ws_size,
                              hipStream_t stream)
{
    const float* Q   = (const float*)d_in[0];
    const float* K   = (const float*)d_in[1];
    const float* V   = (const float*)d_in[2];
    const float* pek = (const float*)d_in[3];
    const float* pev = (const float*)d_in[4];
    float* out  = (float*)d_out;
    float* pbuf = out + (size_t)64 * Sc * Dc;   // p_attn follows output
    float* lws  = (float*)d_ws;                 // 64*1024 f32 row sums (256 KB)

    hipMemsetAsync(d_ws, 0, (size_t)64 * Sc * sizeof(float), stream);
    lsum_zero<<<dim3(256, 64), 256, 0, stream>>>(Q, K, pek, pbuf, lws);
    relattn<<<dim3(8, 64), 256, 0, stream>>>(Q, K, V, pek, pev, out, pbuf, lws);
}

// Round 9
// 372.542 us; speedup vs baseline: 1.1271x; 1.1271x over previous
//
#include <hip/hip_runtime.h>
#include <math.h>

typedef __attribute__((ext_vector_type(8))) short bfrag;
typedef __attribute__((ext_vector_type(4))) float ffrag;

namespace {
constexpr int Sc = 1024, Dc = 64;
constexpr int P2 = 72;          // bf16 LDS pitch (144 B) for MFMA-read tiles
constexpr int PQ = 64;          // Qs pitch — hoist read is one-time, no pad needed
constexpr int PW = 33;          // f32 pitch for Ts/Ws — bank-spread for row reads
constexpr float SCALE = 0.125f; // 1/sqrt(64)
constexpr float S2 = 0.125f * 1.44269504088896f; // SCALE * log2(e): exp(x*SCALE)=exp2(x*S2)
}

__device__ __forceinline__ unsigned short f2bf(float f) {
    unsigned u = __builtin_bit_cast(unsigned, f);
    u += 0x7fffu + ((u >> 16) & 1u);
    return (unsigned short)(u >> 16);
}
__device__ __forceinline__ bfrag pack8(float4 a, float4 b) {
    bfrag r;
    r[0] = (short)f2bf(a.x); r[1] = (short)f2bf(a.y);
    r[2] = (short)f2bf(a.z); r[3] = (short)f2bf(a.w);
    r[4] = (short)f2bf(b.x); r[5] = (short)f2bf(b.y);
    r[6] = (short)f2bf(b.z); r[7] = (short)f2bf(b.w);
    return r;
}
#define MFMA(a, b, c) __builtin_amdgcn_mfma_f32_16x16x32_bf16((a), (b), (c), 0, 0, 0)

// Paired q-tiles (512 blocks, balanced). Pass 2 software-pipelined to ONE
// barrier per kt: window kt = { QK(kt) -> Pt[kt&1] | stage K[kt+1],V[kt] |
// PV(kt-1)+dump(kt-1) from Pt/Vt[(kt-1)&1] }.
// This revision (kernel is LDS-pipe-bound): dump reads Pt as b64 (4 ops, was
// 8 b32), and exp folded to exp2f(fma(c,S2,ts2)) (saves 2 VALU/exp).
__global__ __launch_bounds__(256, 2)
void relattn(const float* __restrict__ Qg, const float* __restrict__ Kg,
             const float* __restrict__ Vg, const float* __restrict__ pek,
             const float* __restrict__ pev, float* __restrict__ outg,
             float* __restrict__ pbuf)
{
    // LDS arena (72448 B, 2 blocks/CU):
    // Ks0 9216 | Ks1 9216 | Vt0 9216 | Vt1 9216 | Pt0 9216 | Pt1 9216 |
    // Ts 8448 | QsArena 8704 (Qs [64][64] bf16 aliased by Ws [64][33] f32 + W0 [64])
    // Ot (64x68 f32 = 17408 B) aliases Ks0+Ks1 (epilogue only).
    __shared__ __align__(16) char smem[72448];
    unsigned short* Ks0 = (unsigned short*)smem;
    unsigned short* Ks1 = (unsigned short*)(smem + 9216);
    unsigned short* Vt0 = (unsigned short*)(smem + 18432);
    unsigned short* Vt1 = (unsigned short*)(smem + 27648);
    unsigned short* Pt0 = (unsigned short*)(smem + 36864);
    unsigned short* Pt1 = (unsigned short*)(smem + 46080);
    float* Ts = (float*)(smem + 55296);                    // [64][33]
    unsigned short* Qs = (unsigned short*)(smem + 63744);  // [64][64]
    float* Ws = (float*)(smem + 63744);                    // [64][33], aliases Qs
    float* W0 = (float*)(smem + 72192);                    // [64]
    float* Ot = (float*)smem;                              // [64][68], aliases Ks0+Ks1

    const int tid  = threadIdx.x;
    const int bh   = blockIdx.y;
    const int wv   = tid >> 6;
    const int lane = tid & 63;
    const int n    = lane & 15;
    const int quad = lane >> 4;

    const float* Qbh = Qg + (size_t)bh * Sc * Dc;
    const float* Kbh = Kg + (size_t)bh * Sc * Dc;
    const float* Vbh = Vg + (size_t)bh * Sc * Dc;
    float* pbh = pbuf + (size_t)bh * Sc * Sc;
    float* obh = outg + (size_t)bh * Sc * Dc;

    const int sr  = tid >> 2;           // staging row 0..63
    const int sc4 = (tid & 3) * 16;     // staging col (floats)
    const int kp  = tid & 31;           // V-transpose k-pair
    const int vd0 = (tid >> 5) * 8;     // V-transpose d base

    // dump-phase coords: thread owns float4 col c4 of rows {rr, 16+rr, 32+rr, 48+rr}
    const int rr = tid >> 4;            // 0..15
    const int c4 = tid & 15;            // 0..15 (float4 col)

    for (int half = 0; half < 2; ++half) {
        const int qt = half ? (15 - (int)blockIdx.x) : (int)blockIdx.x;
        const int qrow = wv * 16 + quad * 4;   // C-layout row base for this lane

        __syncthreads();   // previous half's epilogue fully done with LDS

        // ---- issue K[0] loads first (latency hides under Q/pe_k staging + Ts) ----
        float4 k0a, k0b, k0c, k0d;
        {
            const float* ksrc = Kbh + (size_t)sr * Dc + sc4;
            k0a = *(const float4*)(ksrc);
            k0b = *(const float4*)(ksrc + 4);
            k0c = *(const float4*)(ksrc + 8);
            k0d = *(const float4*)(ksrc + 12);
        }
        // ---- stage Q tile (fp32 -> bf16) ----
        {
            const float* src = Qbh + (size_t)(qt * 64 + sr) * Dc + sc4;
            float4 a = *(const float4*)(src);
            float4 b = *(const float4*)(src + 4);
            float4 c = *(const float4*)(src + 8);
            float4 d = *(const float4*)(src + 12);
            *(bfrag*)&Qs[sr * PQ + sc4]     = pack8(a, b);
            *(bfrag*)&Qs[sr * PQ + sc4 + 8] = pack8(c, d);
        }
        // ---- stage pe_k (rows 0..32) into Ks0; zero rows 33..47 ----
        for (int i = tid; i < 135; i += 256) {          // zero [33*72, 48*72)
            bfrag z = {};
            *(bfrag*)&Ks0[33 * P2 + i * 8] = z;
        }
        if (tid < 132) {
            int r = tid >> 2, c0 = (tid & 3) * 16;
            const float* src = pek + (size_t)r * Dc + c0;
            float4 a = *(const float4*)(src);
            float4 b = *(const float4*)(src + 4);
            float4 c = *(const float4*)(src + 8);
            float4 d = *(const float4*)(src + 12);
            *(bfrag*)&Ks0[r * P2 + c0]     = pack8(a, b);
            *(bfrag*)&Ks0[r * P2 + c0 + 8] = pack8(c, d);
        }
        __syncthreads();

        // ---- hoist Q A-frags (row = wv*16+n, k = d); Qs dead afterwards ----
        bfrag qa0 = *(bfrag*)&Qs[(wv * 16 + n) * PQ + quad * 8];
        bfrag qa1 = *(bfrag*)&Qs[(wv * 16 + n) * PQ + 32 + quad * 8];

        // ---- Ts = Q . pe_k^T via MFMA (j in 0..47, keep j<=32) ----
        #pragma unroll
        for (int sub = 0; sub < 3; ++sub) {
            bfrag b0 = *(bfrag*)&Ks0[(sub * 16 + n) * P2 + quad * 8];
            bfrag b1 = *(bfrag*)&Ks0[(sub * 16 + n) * P2 + 32 + quad * 8];
            ffrag c = {};
            c = MFMA(qa0, b0, c);
            c = MFMA(qa1, b1, c);
            int j = sub * 16 + n;
            if (j <= 32) {
                #pragma unroll
                for (int reg = 0; reg < 4; ++reg)
                    Ts[(qrow + reg) * PW + j] = c[reg];
            }
        }
        // ---- pack K[0] -> Ks1 (waits k0*); issue K[1] prefetch ----
        *(bfrag*)&Ks1[sr * P2 + sc4]     = pack8(k0a, k0b);
        *(bfrag*)&Ks1[sr * P2 + sc4 + 8] = pack8(k0c, k0d);
        float4 pka, pkb, pkc, pkd;
        if (qt >= 1) {
            const float* ksrc = Kbh + (size_t)(64 + sr) * Dc + sc4;
            pka = *(const float4*)(ksrc);
            pkb = *(const float4*)(ksrc + 4);
            pkc = *(const float4*)(ksrc + 8);
            pkd = *(const float4*)(ksrc + 12);
        }
        __syncthreads();   // Ts + K[0] visible; all waves hoisted Q -> Qs free

        float ts2[4];   // pre-scaled for exp2: exp((c+ts0)*SCALE) = exp2(fma(c,S2,ts2))
        #pragma unroll
        for (int reg = 0; reg < 4; ++reg) ts2[reg] = Ts[(qrow + reg) * PW] * S2;

        // ---- zero Ws (aliases Qs; safe after barrier) ----
        for (int idx = tid; idx < 64 * PW; idx += 256) Ws[idx] = 0.f;

        // ---- zero-fill fully-masked p region (cols >= (qt+1)*64) ----
        {
            const int zb = (qt + 1) * 64;
            if (zb < Sc) {
                const int z4 = (Sc - zb) >> 2;
                const float4 z = make_float4(0.f, 0.f, 0.f, 0.f);
                for (int r = 0; r < 64; ++r) {
                    float4* rp = (float4*)(pbh + (size_t)(qt * 64 + r) * Sc + zb);
                    for (int cz = tid; cz < z4; cz += 256) rp[cz] = z;
                }
            }
        }

        // ================= pass 1: l = sum(exp(s)), 1 barrier/kt =================
        float lsum[4] = {0.f, 0.f, 0.f, 0.f};
        for (int kt = 0; kt <= qt; ++kt) {
            const bool bnd = (kt >= qt - 1);
            unsigned short* Kc = (kt & 1) ? Ks0 : Ks1;   // K[0] lives in Ks1
            unsigned short* Kn = (kt & 1) ? Ks1 : Ks0;
            #pragma unroll
            for (int sub = 0; sub < 4; ++sub) {
                bfrag b0 = *(bfrag*)&Kc[(sub * 16 + n) * P2 + quad * 8];
                bfrag b1 = *(bfrag*)&Kc[(sub * 16 + n) * P2 + 32 + quad * 8];
                ffrag c = {};
                c = MFMA(qa0, b0, c);
                c = MFMA(qa1, b1, c);
                const int k = kt * 64 + sub * 16 + n;
                if (!bnd) {
                    #pragma unroll
                    for (int reg = 0; reg < 4; ++reg)
                        lsum[reg] += exp2f(fmaf(c[reg], S2, ts2[reg]));
                } else {
                    #pragma unroll
                    for (int reg = 0; reg < 4; ++reg) {
                        int jrel = k - (qt * 64 + qrow + reg) + 32;
                        if (jrel <= 32) {
                            int jcl = jrel < 0 ? 0 : jrel;
                            lsum[reg] += exp2f(fmaf(c[reg] + Ts[(qrow + reg) * PW + jcl], S2, 0.f));
                        }
                    }
                }
            }
            if (kt < qt) {     // stage K[kt+1] (regs prefetched last iter)
                *(bfrag*)&Kn[sr * P2 + sc4]     = pack8(pka, pkb);
                *(bfrag*)&Kn[sr * P2 + sc4 + 8] = pack8(pkc, pkd);
            }
            if (kt + 2 <= qt) {   // issue K[kt+2]
                const float* ksrc = Kbh + (size_t)((kt + 2) * 64 + sr) * Dc + sc4;
                pka = *(const float4*)(ksrc);
                pkb = *(const float4*)(ksrc + 4);
                pkc = *(const float4*)(ksrc + 8);
                pkd = *(const float4*)(ksrc + 12);
            }
            __syncthreads();
        }
        float rinv[4];
        #pragma unroll
        for (int reg = 0; reg < 4; ++reg) {
            float l = lsum[reg];
            l += __shfl_xor(l, 1);
            l += __shfl_xor(l, 2);
            l += __shfl_xor(l, 4);
            l += __shfl_xor(l, 8);
            rinv[reg] = 1.f / l;
        }

        // ---- pass-2 prologue: restage K[0]->Ks0 (L2-hot); issue K[1], V[0] ----
        {
            const float* ksrc = Kbh + (size_t)sr * Dc + sc4;
            float4 a = *(const float4*)(ksrc);
            float4 b = *(const float4*)(ksrc + 4);
            float4 c = *(const float4*)(ksrc + 8);
            float4 d = *(const float4*)(ksrc + 12);
            *(bfrag*)&Ks0[sr * P2 + sc4]     = pack8(a, b);
            *(bfrag*)&Ks0[sr * P2 + sc4 + 8] = pack8(c, d);
        }
        if (qt >= 1) {
            const float* ksrc = Kbh + (size_t)(64 + sr) * Dc + sc4;
            pka = *(const float4*)(ksrc);
            pkb = *(const float4*)(ksrc + 4);
            pkc = *(const float4*)(ksrc + 8);
            pkd = *(const float4*)(ksrc + 12);
        }
        float4 pva, pvb, pvc, pvd;
        {
            const float* vsrc = Vbh + (size_t)(2 * kp) * Dc + vd0;
            pva = *(const float4*)(vsrc);
            pvb = *(const float4*)(vsrc + 4);
            pvc = *(const float4*)(vsrc + Dc);
            pvd = *(const float4*)(vsrc + Dc + 4);
        }
        __syncthreads();   // K[0] visible

        // ====== pass 2 (pipelined, 1 barrier/kt): QK(kt) || PV(kt-1)+dump ======
        ffrag oacc[4];
        #pragma unroll
        for (int i = 0; i < 4; ++i) { ffrag z = {}; oacc[i] = z; }

        for (int kt = 0; kt <= qt; ++kt) {
            const bool bnd = (kt >= qt - 1);
            unsigned short* Kc  = (kt & 1) ? Ks1 : Ks0;   // K[kt] (K[0] in Ks0)
            unsigned short* Kn  = (kt & 1) ? Ks0 : Ks1;
            unsigned short* Vc  = (kt & 1) ? Vt1 : Vt0;   // stage target for V[kt]
            unsigned short* Vp  = (kt & 1) ? Vt0 : Vt1;   // V[kt-1] for PV
            unsigned short* Ptc = (kt & 1) ? Pt1 : Pt0;   // QK(kt) writes
            unsigned short* Ptp = (kt & 1) ? Pt0 : Pt1;   // PV(kt-1) reads

            // ---- QK(kt): scores -> Ptc (bf16, normalized), rel-v capture ----
            #pragma unroll
            for (int sub = 0; sub < 4; ++sub) {
                bfrag b0 = *(bfrag*)&Kc[(sub * 16 + n) * P2 + quad * 8];
                bfrag b1 = *(bfrag*)&Kc[(sub * 16 + n) * P2 + 32 + quad * 8];
                ffrag c = {};
                c = MFMA(qa0, b0, c);
                c = MFMA(qa1, b1, c);
                const int k = kt * 64 + sub * 16 + n;
                if (!bnd) {
                    #pragma unroll
                    for (int reg = 0; reg < 4; ++reg) {
                        float p = exp2f(fmaf(c[reg], S2, ts2[reg])) * rinv[reg];
                        Ptc[(qrow + reg) * P2 + sub * 16 + n] = (unsigned short)f2bf(p);
                    }
                } else {
                    #pragma unroll
                    for (int reg = 0; reg < 4; ++reg) {
                        int jrel = k - (qt * 64 + qrow + reg) + 32;
                        float p = 0.f;
                        if (jrel <= 32) {
                            int jcl = jrel < 0 ? 0 : jrel;
                            p = exp2f((c[reg] + Ts[(qrow + reg) * PW + jcl]) * S2) * rinv[reg];
                        }
                        Ptc[(qrow + reg) * P2 + sub * 16 + n] = (unsigned short)f2bf(p);
                        if ((unsigned)(jrel - 1) < 32u) Ws[(qrow + reg) * PW + jrel - 1] = p;
                    }
                }
            }
            // ---- stage K[kt+1] -> Kn; V[kt] -> Vc (regs from last window) ----
            if (kt < qt) {
                *(bfrag*)&Kn[sr * P2 + sc4]     = pack8(pka, pkb);
                *(bfrag*)&Kn[sr * P2 + sc4 + 8] = pack8(pkc, pkd);
            }
            {
                float r0[8] = {pva.x, pva.y, pva.z, pva.w, pvb.x, pvb.y, pvb.z, pvb.w};
                float r1[8] = {pvc.x, pvc.y, pvc.z, pvc.w, pvd.x, pvd.y, pvd.z, pvd.w};
                #pragma unroll
                for (int i = 0; i < 8; ++i) {
                    unsigned pk = (unsigned)f2bf(r0[i]) | ((unsigned)f2bf(r1[i]) << 16);
                    *(unsigned*)&Vc[(vd0 + i) * P2 + 2 * kp] = pk;   // Vc[d][k]
                }
            }
            // ---- issue next prefetches ----
            if (kt + 2 <= qt) {
                const float* ksrc = Kbh + (size_t)((kt + 2) * 64 + sr) * Dc + sc4;
                pka = *(const float4*)(ksrc);
                pkb = *(const float4*)(ksrc + 4);
                pkc = *(const float4*)(ksrc + 8);
                pkd = *(const float4*)(ksrc + 12);
            }
            if (kt + 1 <= qt) {
                const float* vsrc = Vbh + (size_t)((kt + 1) * 64 + 2 * kp) * Dc + vd0;
                pva = *(const float4*)(vsrc);
                pvb = *(const float4*)(vsrc + 4);
                pvc = *(const float4*)(vsrc + Dc);
                pvd = *(const float4*)(vsrc + Dc + 4);
            }
            // ---- PV(kt-1) + dump(kt-1): independent of QK(kt) ----
            if (kt >= 1) {
                bfrag pb0 = *(bfrag*)&Ptp[(wv * 16 + n) * P2 + quad * 8];
                bfrag pb1 = *(bfrag*)&Ptp[(wv * 16 + n) * P2 + 32 + quad * 8];
                #pragma unroll
                for (int ds = 0; ds < 4; ++ds) {
                    bfrag va0 = *(bfrag*)&Vp[(ds * 16 + n) * P2 + quad * 8];
                    bfrag va1 = *(bfrag*)&Vp[(ds * 16 + n) * P2 + 32 + quad * 8];
                    oacc[ds] = MFMA(va0, pb0, oacc[ds]);
                    oacc[ds] = MFMA(va1, pb1, oacc[ds]);
                }
                float* base = pbh + ((size_t)(qt * 64 + rr) * Sc + (kt - 1) * 64 + c4 * 4);
                #pragma unroll
                for (int step = 0; step < 4; ++step) {
                    const int r = step * 16 + rr;
                    uint2 two = *(const uint2*)&Ptp[r * P2 + c4 * 4];   // ds_read_b64
                    float4 v;
                    v.x = __builtin_bit_cast(float, (two.x & 0xffffu) << 16);
                    v.y = __builtin_bit_cast(float, two.x & 0xffff0000u);
                    v.z = __builtin_bit_cast(float, (two.y & 0xffffu) << 16);
                    v.w = __builtin_bit_cast(float, two.y & 0xffff0000u);
                    *(float4*)(base + (size_t)(step * 16) * Sc) = v;
                }
            }
            __syncthreads();   // window boundary
        }
        // ---- drain: PV(qt) + dump(qt) ----
        {
            unsigned short* Ptp = (qt & 1) ? Pt1 : Pt0;
            unsigned short* Vp  = (qt & 1) ? Vt1 : Vt0;
            bfrag pb0 = *(bfrag*)&Ptp[(wv * 16 + n) * P2 + quad * 8];
            bfrag pb1 = *(bfrag*)&Ptp[(wv * 16 + n) * P2 + 32 + quad * 8];
            #pragma unroll
            for (int ds = 0; ds < 4; ++ds) {
                bfrag va0 = *(bfrag*)&Vp[(ds * 16 + n) * P2 + quad * 8];
                bfrag va1 = *(bfrag*)&Vp[(ds * 16 + n) * P2 + 32 + quad * 8];
                oacc[ds] = MFMA(va0, pb0, oacc[ds]);
                oacc[ds] = MFMA(va1, pb1, oacc[ds]);
            }
            float* base = pbh + ((size_t)(qt * 64 + rr) * Sc + qt * 64 + c4 * 4);
            #pragma unroll
            for (int step = 0; step < 4; ++step) {
                const int r = step * 16 + rr;
                uint2 two = *(const uint2*)&Ptp[r * P2 + c4 * 4];   // ds_read_b64
                float4 v;
                v.x = __builtin_bit_cast(float, (two.x & 0xffffu) << 16);
                v.y = __builtin_bit_cast(float, two.x & 0xffff0000u);
                v.z = __builtin_bit_cast(float, (two.y & 0xffffu) << 16);
                v.w = __builtin_bit_cast(float, two.y & 0xffff0000u);
                *(float4*)(base + (size_t)(step * 16) * Sc) = v;
            }
        }
        __syncthreads();   // all PV/dump reads done before epilogue prep writes

        // ================= epilogue: rel-v term + store O =================
        if (tid < 64) {
            float s = 0.f;
            #pragma unroll
            for (int j = 0; j < 32; ++j) s += Ws[tid * PW + j];   // pitch-33: conflict-free
            W0[tid] = 1.f - s;   // mass of far past (jrel<=0)
        }
        {   // Pt0[q][jj] <- Ws (bf16), jj = jrel-1 in 0..31
            int q = tid >> 2, j0 = (tid & 3) * 8;
            #pragma unroll
            for (int i = 0; i < 8; i += 2) {
                unsigned pk = (unsigned)f2bf(Ws[q * PW + j0 + i]) |
                              ((unsigned)f2bf(Ws[q * PW + j0 + i + 1]) << 16);
                *(unsigned*)&Pt0[q * P2 + j0 + i] = pk;
            }
        }
        {   // Vt0[d][jj] <- pe_v[jj+1][d]
            int jj = tid >> 3, d0 = (tid & 7) * 8;
            const float* src = pev + (size_t)(jj + 1) * Dc + d0;
            float4 a = *(const float4*)(src);
            float4 b = *(const float4*)(src + 4);
            float vr[8] = {a.x, a.y, a.z, a.w, b.x, b.y, b.z, b.w};
            #pragma unroll
            for (int i = 0; i < 8; ++i)
                Vt0[(d0 + i) * P2 + jj] = (unsigned short)f2bf(vr[i]);
        }
        __syncthreads();   // Pt0/Vt0/W0 prep visible
        {
            bfrag pb = *(bfrag*)&Pt0[(wv * 16 + n) * P2 + quad * 8];
            #pragma unroll
            for (int ds = 0; ds < 4; ++ds) {
                bfrag va = *(bfrag*)&Vt0[(ds * 16 + n) * P2 + quad * 8];
                oacc[ds] = MFMA(va, pb, oacc[ds]);
            }
        }
        float w0q = W0[wv * 16 + n];
        // Ot aliases Ks0/Ks1 only (dead) — no barrier needed before write
        #pragma unroll
        for (int ds = 0; ds < 4; ++ds) {
            float4 ov;
            ov.x = oacc[ds][0] + w0q * pev[ds * 16 + quad * 4 + 0];
            ov.y = oacc[ds][1] + w0q * pev[ds * 16 + quad * 4 + 1];
            ov.z = oacc[ds][2] + w0q * pev[ds * 16 + quad * 4 + 2];
            ov.w = oacc[ds][3] + w0q * pev[ds * 16 + quad * 4 + 3];
            *(float4*)&Ot[(wv * 16 + n) * 68 + ds * 16 + quad * 4] = ov;
        }
        __syncthreads();
        {
            int r = tid >> 2, c0 = (tid & 3) * 16;
            float* dst = obh + (size_t)(qt * 64 + r) * Dc + c0;
            *(float4*)(dst)      = *(float4*)&Ot[r * 68 + c0];
            *(float4*)(dst + 4)  = *(float4*)&Ot[r * 68 + c0 + 4];
            *(float4*)(dst + 8)  = *(float4*)&Ot[r * 68 + c0 + 8];
            *(float4*)(dst + 12) = *(float4*)&Ot[r * 68 + c0 + 12];
        }
    }
}

extern "C" void kernel_launch(void* const* d_in, const int* in_sizes, int n_in,
                              void* d_out, int out_size, void* d_ws, size_t ws_size,
                              hipStream_t stream)
{
    const float* Q   = (const float*)d_in[0];
    const float* K   = (const float*)d_in[1];
    const float* V   = (const float*)d_in[2];
    const float* pek = (const float*)d_in[3];
    const float* pev = (const float*)d_in[4];
    float* out  = (float*)d_out;
    float* pbuf = out + (size_t)64 * Sc * Dc;   // p_attn follows output

    dim3 grid(8, 64);   // paired q-tiles (b, 15-b): uniform work per block
    relattn<<<grid, 256, 0, stream>>>(Q, K, V, pek, pev, out, pbuf);
}